// Round 9
// baseline (252.775 us; speedup 1.0000x reference)
//
#include <hip/hip_runtime.h>
#include <math.h>

#define B_  2
#define S_  2048
#define D_  1024
#define H_  16
#define DH_ 64
#define M_  (B_ * S_)   // 4096

typedef _Float16 half_t;
typedef __attribute__((ext_vector_type(8))) _Float16 h8;
typedef __attribute__((ext_vector_type(4))) _Float16 h4;
typedef __attribute__((ext_vector_type(4))) float   f32x4;

#define LOG2E 1.44269504088896f

// async global->LDS, 16 B per lane (lane-contiguous dest, m104/m108)
__device__ __forceinline__ void gll16(const half_t* g, half_t* l) {
    __builtin_amdgcn_global_load_lds(
        (__attribute__((address_space(1))) const void*)g,
        (__attribute__((address_space(3))) void*)l, 16, 0, 0);
}

// ---------------------------------------------------------------------------
// Prepass (fused): blocks 0..2047 convert x fp32->fp16; blocks 2048..3583
// transpose W [k][n] fp32 -> Wt [n][k] fp16 (3 matrices).
// ---------------------------------------------------------------------------
__global__ __launch_bounds__(256) void prep_k(
    const float* __restrict__ x, half_t* __restrict__ xh,
    const float* __restrict__ Wq, const float* __restrict__ Wk,
    const float* __restrict__ Wv, half_t* __restrict__ Wt)
{
    const int bx = blockIdx.x;
    if (bx < 2048) {
        const size_t i = ((size_t)bx * 256 + threadIdx.x) * 8;
        const float4 a = *(const float4*)(x + i);
        const float4 b = *(const float4*)(x + i + 4);
        h8 o;
        o[0] = (half_t)a.x; o[1] = (half_t)a.y; o[2] = (half_t)a.z; o[3] = (half_t)a.w;
        o[4] = (half_t)b.x; o[5] = (half_t)b.y; o[6] = (half_t)b.z; o[7] = (half_t)b.w;
        *(h8*)(xh + i) = o;
    } else {
        const int gb    = bx - 2048;                 // 0..1535
        const int which = gb >> 9;
        const float* __restrict__ W = (which == 0) ? Wq : (which == 1) ? Wk : Wv;
        half_t* __restrict__ T = Wt + (size_t)which * D_ * D_;
        const int gw   = (gb & 511) * 4 + (threadIdx.x >> 6);   // 0..2047
        const int lane = threadIdx.x & 63;
        const int n    = (gw & 15) * 64 + lane;
        const int k0   = (gw >> 4) * 8;
        h8 o;
        #pragma unroll
        for (int t = 0; t < 8; ++t) o[t] = (half_t)W[(size_t)(k0 + t) * D_ + n];
        *(h8*)(T + (size_t)n * D_ + k0) = o;
    }
}

// ---------------------------------------------------------------------------
// Kernel 1: fused QKV projection.  128x128 tile, BK=32, DOUBLE-BUFFERED
// global_load_lds with post-barrier prefetch: one __syncthreads per k-step,
// DMA for step t+1 overlaps MFMA of step t (the vmcnt(0) drain at the next
// barrier lands after a full compute phase).  Unpadded stride-32 LDS:
// frag-read banks (16r+4q+j)%32 give 2-way max (free).  XCD-swizzled grid.
// Epilogue: Q = tanh-GELU * log2e, K natural, V pre-transposed Vt[bh][d][s].
// ---------------------------------------------------------------------------
__global__ __launch_bounds__(256) void qkv_gemm_f16(
    const half_t* __restrict__ xh, const half_t* __restrict__ Wt,
    const float* __restrict__ bq, const float* __restrict__ bk,
    const float* __restrict__ bv,
    half_t* __restrict__ Qo, half_t* __restrict__ Ko, half_t* __restrict__ Vt)
{
    const int bi = blockIdx.x;                       // 0..767
    const int mt = (bi & 7) * 4 + ((bi >> 3) & 3);   // 0..31
    const int nt = bi >> 5;                          // 0..23
    const int m0 = mt * 128;
    const int n0g = nt * 128;
    const int which = n0g >> 10;
    const int n0    = n0g & 1023;
    const half_t* __restrict__ Wp  = Wt + (size_t)which * D_ * D_;
    const float* __restrict__ bias = (which == 0) ? bq : (which == 1) ? bk : bv;

    const int tid = threadIdx.x, lane = tid & 63, wave = tid >> 6;
    const int wm = (wave >> 1) * 64, wn = (wave & 1) * 64;
    const int ln = lane & 15, quad = lane >> 4;

    __shared__ __align__(16) half_t As[2][128 * 32];   // 8 KB per buffer
    __shared__ __align__(16) half_t Bs[2][128 * 32];

    f32x4 acc[4][4];
    #pragma unroll
    for (int i = 0; i < 4; ++i)
        #pragma unroll
        for (int j = 0; j < 4; ++j) acc[i][j] = (f32x4){0.f, 0.f, 0.f, 0.f};

    // prologue: stage k-step 0 into buffer 0
    {
        #pragma unroll
        for (int l = 0; l < 2; ++l) {
            const int c = tid + l * 256;             // 16B-chunk 0..511
            const int r = c >> 2, c8 = c & 3;
            gll16(xh + (size_t)(m0 + r) * D_ + c8 * 8, &As[0][c * 8]);
            gll16(Wp + (size_t)(n0 + r) * D_ + c8 * 8, &Bs[0][c * 8]);
        }
    }

    for (int kt = 0; kt < 32; ++kt) {
        __syncthreads();                 // drains DMA(kt); compute(kt-1) done
        if (kt + 1 < 32) {               // prefetch kt+1 into other buffer
            const int k0 = (kt + 1) * 32;
            const int pb = (kt + 1) & 1;
            #pragma unroll
            for (int l = 0; l < 2; ++l) {
                const int c = tid + l * 256;
                const int r = c >> 2, c8 = c & 3;
                gll16(xh + (size_t)(m0 + r) * D_ + k0 + c8 * 8, &As[pb][c * 8]);
                gll16(Wp + (size_t)(n0 + r) * D_ + k0 + c8 * 8, &Bs[pb][c * 8]);
            }
        }
        const int p = kt & 1;
        h8 af[4], bf[4];
        #pragma unroll
        for (int i = 0; i < 4; ++i)
            af[i] = *(const h8*)&As[p][(wm + i * 16 + ln) * 32 + quad * 8];
        #pragma unroll
        for (int j = 0; j < 4; ++j)
            bf[j] = *(const h8*)&Bs[p][(wn + j * 16 + ln) * 32 + quad * 8];
        #pragma unroll
        for (int i = 0; i < 4; ++i)
            #pragma unroll
            for (int j = 0; j < 4; ++j)
                acc[i][j] = __builtin_amdgcn_mfma_f32_16x16x32_f16(
                    af[i], bf[j], acc[i][j], 0, 0, 0);
    }

    if (which == 2) {
        #pragma unroll
        for (int j = 0; j < 4; ++j) {
            const int col = n0 + wn + j * 16 + ln;
            const int h = col >> 6, d = col & 63;
            const float bb = bias[col];
            #pragma unroll
            for (int i = 0; i < 4; ++i) {
                const int sg = m0 + wm + i * 16 + quad * 4;
                const int b  = sg >> 11, srow = sg & 2047;
                h4 pv;
                #pragma unroll
                for (int r = 0; r < 4; ++r) pv[r] = (half_t)(acc[i][j][r] + bb);
                *(h4*)(Vt + (((size_t)(b * H_ + h) * DH_ + d) * S_ + srow)) = pv;
            }
        }
    } else {
        half_t* __restrict__ out = (which == 0) ? Qo : Ko;
        #pragma unroll
        for (int j = 0; j < 4; ++j) {
            const int col = n0 + wn + j * 16 + ln;
            const float bb = bias[col];
            #pragma unroll
            for (int i = 0; i < 4; ++i) {
                #pragma unroll
                for (int r = 0; r < 4; ++r) {
                    const int row = m0 + wm + i * 16 + quad * 4 + r;
                    float t = acc[i][j][r] + bb;
                    if (which == 0) {
                        const float u = t * fmaf(t * t, 0.0356774081f, 0.7978845608f);
                        const float e = __builtin_amdgcn_exp2f(u * -2.88539008178f);
                        t = t * __builtin_amdgcn_rcpf(1.0f + e) * LOG2E;
                    }
                    out[(size_t)row * D_ + col] = (half_t)t;
                }
            }
        }
    }
}

// ---------------------------------------------------------------------------
// Kernel 2: flash attention.  2-wave blocks, 64 q-rows (2 q-groups/wave),
// 1024 blocks.  DOUBLE-BUFFERED K/V staging with post-barrier prefetch:
// ONE __syncthreads per k-tile; the DMA for tile t+1 is issued right after
// the barrier and overlaps QK/softmax/PV of tile t.  XOR-chunk-swizzled
// unpadded tiles (conflict-free b128 frag reads, lane-contiguous DMA).
// Logits pre-scaled by log2e (p = 2^x); conditional O/l rescale; l via
// ones-MFMA.  LDS = 2*(8+8) + 9.2 = 41.2 KB -> 3 blocks/CU.
// ---------------------------------------------------------------------------
__global__ __launch_bounds__(128) void attn_f16(
    const half_t* __restrict__ Q, const half_t* __restrict__ K,
    const half_t* __restrict__ Vt, float* __restrict__ out)
{
    const int tid  = threadIdx.x;
    const int lane = tid & 63;
    const int wave = tid >> 6;          // 0..1
    const int ln   = lane & 15;
    const int quad = lane >> 4;

    const int bi = blockIdx.x;                      // 0..1023
    const int bh = (bi & 7) * 4 + ((bi >> 3) & 3);  // 0..31 (XCD band)
    const int q0 = (bi >> 5) * 64;                  // 0..1984
    const int b  = bh >> 4;
    const int h  = bh & 15;

    const half_t* __restrict__ Qb  = Q  + (size_t)b * S_ * D_ + h * DH_;
    const half_t* __restrict__ Kb  = K  + (size_t)b * S_ * D_ + h * DH_;
    const half_t* __restrict__ Vtb = Vt + (size_t)bh * DH_ * S_;

    __shared__ __align__(16) half_t Ks[2][64 * 64];   // 8 KB per buffer
    __shared__ __align__(16) half_t Vs[2][64 * 64];
    __shared__ __align__(16) half_t Ps[64][72];       // wave-private bands

    // ---- Q fragments, direct from global (one-time) ----
    const int qra = q0 + wave * 32 + ln;
    const h8 qa0 = *(const h8*)(Qb + (size_t)qra * D_ + quad * 8);
    const h8 qa1 = *(const h8*)(Qb + (size_t)qra * D_ + 32 + quad * 8);
    const h8 qc0 = *(const h8*)(Qb + (size_t)(qra + 16) * D_ + quad * 8);
    const h8 qc1 = *(const h8*)(Qb + (size_t)(qra + 16) * D_ + 32 + quad * 8);

    h8 ones8;
    #pragma unroll
    for (int t = 0; t < 8; ++t) ones8[t] = (half_t)1.0f;

    f32x4 Oa[4], Ob[4];
    #pragma unroll
    for (int j = 0; j < 4; ++j) {
        Oa[j] = (f32x4){0.f, 0.f, 0.f, 0.f};
        Ob[j] = (f32x4){0.f, 0.f, 0.f, 0.f};
    }
    f32x4 la = (f32x4){0.f, 0.f, 0.f, 0.f};
    f32x4 lb = (f32x4){0.f, 0.f, 0.f, 0.f};
    float m_a = -INFINITY, m_b = -INFINITY;

    // prologue: stage k-tile 0 into buffer 0
    #pragma unroll
    for (int l = 0; l < 4; ++l) {
        const int c  = tid + l * 128;
        const int r  = c >> 3, c0 = c & 7;
        const int cs = c0 ^ (r & 7);
        gll16(Kb  + (size_t)r * D_ + cs * 8, &Ks[0][c * 8]);
        gll16(Vtb + (size_t)r * S_ + cs * 8, &Vs[0][c * 8]);
    }

    for (int t = 0; t < 32; ++t) {
        __syncthreads();                  // drains DMA(t); compute(t-1) done
        if (t + 1 < 32) {                 // prefetch t+1 into other buffer
            const int k0 = (t + 1) * 64;
            const int pb = (t + 1) & 1;
            #pragma unroll
            for (int l = 0; l < 4; ++l) {
                const int c  = tid + l * 128;
                const int r  = c >> 3, c0 = c & 7;
                const int cs = c0 ^ (r & 7);
                gll16(Kb  + (size_t)(k0 + r) * D_ + cs * 8, &Ks[pb][c * 8]);
                gll16(Vtb + (size_t)r * S_ + k0 + cs * 8,   &Vs[pb][c * 8]);
            }
        }
        const int p = t & 1;

        // ---- S^T = K Q^T for both q-groups ----
        f32x4 sa[4], sb[4];
        #pragma unroll
        for (int j = 0; j < 4; ++j) {
            const int rK = j * 16 + ln;
            const h8 ka0 = *(const h8*)&Ks[p][rK * 64 + ((quad)     ^ (rK & 7)) * 8];
            const h8 ka1 = *(const h8*)&Ks[p][rK * 64 + ((quad + 4) ^ (rK & 7)) * 8];
            f32x4 tt = (f32x4){0.f, 0.f, 0.f, 0.f};
            tt = __builtin_amdgcn_mfma_f32_16x16x32_f16(ka0, qa0, tt, 0, 0, 0);
            tt = __builtin_amdgcn_mfma_f32_16x16x32_f16(ka1, qa1, tt, 0, 0, 0);
            sa[j] = tt;
            f32x4 u = (f32x4){0.f, 0.f, 0.f, 0.f};
            u = __builtin_amdgcn_mfma_f32_16x16x32_f16(ka0, qc0, u, 0, 0, 0);
            u = __builtin_amdgcn_mfma_f32_16x16x32_f16(ka1, qc1, u, 0, 0, 0);
            sb[j] = u;
        }

        // ---- online softmax (log2 domain), conditional rescale ----
        float mxa = sa[0][0], mxb = sb[0][0];
        #pragma unroll
        for (int j = 0; j < 4; ++j)
            #pragma unroll
            for (int r = 0; r < 4; ++r) {
                mxa = fmaxf(mxa, sa[j][r]);
                mxb = fmaxf(mxb, sb[j][r]);
            }
        mxa = fmaxf(mxa, __shfl_xor(mxa, 16, 64));
        mxa = fmaxf(mxa, __shfl_xor(mxa, 32, 64));
        mxb = fmaxf(mxb, __shfl_xor(mxb, 16, 64));
        mxb = fmaxf(mxb, __shfl_xor(mxb, 32, 64));

        if (__ballot(mxa > m_a || mxb > m_b)) {
            const float mna = fmaxf(m_a, mxa);
            const float mnb = fmaxf(m_b, mxb);
            const float ala = __builtin_amdgcn_exp2f(m_a - mna);
            const float alb = __builtin_amdgcn_exp2f(m_b - mnb);
            m_a = mna; m_b = mnb;
            float ra[4], rb[4];
            #pragma unroll
            for (int r = 0; r < 4; ++r) {
                ra[r] = __shfl(ala, quad * 4 + r, 64);
                rb[r] = __shfl(alb, quad * 4 + r, 64);
            }
            #pragma unroll
            for (int r = 0; r < 4; ++r) {
                la[r] *= ra[r]; lb[r] *= rb[r];
                #pragma unroll
                for (int j = 0; j < 4; ++j) { Oa[j][r] *= ra[r]; Ob[j][r] *= rb[r]; }
            }
        }

        // p = 2^(s - m), h4-packed b64 writes into wave-private bands
        #pragma unroll
        for (int j = 0; j < 4; ++j) {
            h4 pva, pvb;
            #pragma unroll
            for (int r = 0; r < 4; ++r) {
                pva[r] = (half_t)__builtin_amdgcn_exp2f(sa[j][r] - m_a);
                pvb[r] = (half_t)__builtin_amdgcn_exp2f(sb[j][r] - m_b);
            }
            *(h4*)&Ps[wave * 32 + ln][j * 16 + quad * 4]      = pva;
            *(h4*)&Ps[wave * 32 + 16 + ln][j * 16 + quad * 4] = pvb;
        }

        // ---- O += P V, l += P 1 (both q-groups share each V fragment) ----
        const h8 pa0 = *(const h8*)&Ps[wave * 32 + ln][quad * 8];
        const h8 pa1 = *(const h8*)&Ps[wave * 32 + ln][32 + quad * 8];
        const h8 pb0 = *(const h8*)&Ps[wave * 32 + 16 + ln][quad * 8];
        const h8 pb1 = *(const h8*)&Ps[wave * 32 + 16 + ln][32 + quad * 8];
        #pragma unroll
        for (int j = 0; j < 4; ++j) {
            const int rV = j * 16 + ln;
            const h8 vb0 = *(const h8*)&Vs[p][rV * 64 + ((quad)     ^ (rV & 7)) * 8];
            const h8 vb1 = *(const h8*)&Vs[p][rV * 64 + ((quad + 4) ^ (rV & 7)) * 8];
            Oa[j] = __builtin_amdgcn_mfma_f32_16x16x32_f16(pa0, vb0, Oa[j], 0, 0, 0);
            Oa[j] = __builtin_amdgcn_mfma_f32_16x16x32_f16(pa1, vb1, Oa[j], 0, 0, 0);
            Ob[j] = __builtin_amdgcn_mfma_f32_16x16x32_f16(pb0, vb0, Ob[j], 0, 0, 0);
            Ob[j] = __builtin_amdgcn_mfma_f32_16x16x32_f16(pb1, vb1, Ob[j], 0, 0, 0);
        }
        la = __builtin_amdgcn_mfma_f32_16x16x32_f16(pa0, ones8, la, 0, 0, 0);
        la = __builtin_amdgcn_mfma_f32_16x16x32_f16(pa1, ones8, la, 0, 0, 0);
        lb = __builtin_amdgcn_mfma_f32_16x16x32_f16(pb0, ones8, lb, 0, 0, 0);
        lb = __builtin_amdgcn_mfma_f32_16x16x32_f16(pb1, ones8, lb, 0, 0, 0);
    }

    // ---- epilogue: normalize, store fp32 ----
    #pragma unroll
    for (int r = 0; r < 4; ++r) {
        const float iva = 1.0f / la[r];
        const float ivb = 1.0f / lb[r];
        const int rowa = q0 + wave * 32 + quad * 4 + r;
        const int rowb = rowa + 16;
        #pragma unroll
        for (int j = 0; j < 4; ++j) {
            out[((size_t)b * S_ + rowa) * D_ + h * DH_ + j * 16 + ln] = Oa[j][r] * iva;
            out[((size_t)b * S_ + rowb) * D_ + h * DH_ + j * 16 + ln] = Ob[j][r] * ivb;
        }
    }
}

// ---------------------------------------------------------------------------
extern "C" void kernel_launch(void* const* d_in, const int* in_sizes, int n_in,
                              void* d_out, int out_size, void* d_ws, size_t ws_size,
                              hipStream_t stream) {
    const float* x  = (const float*)d_in[0];
    const float* Wq = (const float*)d_in[1];
    const float* bq = (const float*)d_in[2];
    const float* Wk = (const float*)d_in[3];
    const float* bk = (const float*)d_in[4];
    const float* Wv = (const float*)d_in[5];
    const float* bv = (const float*)d_in[6];
    float* out = (float*)d_out;

    const size_t nmd = (size_t)M_ * D_;   // 4M
    const size_t ndd = (size_t)D_ * D_;   // 1M
    half_t* xh  = (half_t*)d_ws;          // 4M halves
    half_t* Wt  = xh + nmd;               // 3M
    half_t* Qh  = Wt + 3 * ndd;           // 4M
    half_t* Kh  = Qh + nmd;               // 4M
    half_t* Vtw = Kh + nmd;               // 4M  (38 MB total)

    prep_k<<<2048 + 1536, 256, 0, stream>>>(x, xh, Wq, Wk, Wv, Wt);
    qkv_gemm_f16<<<768, 256, 0, stream>>>(xh, Wt, bq, bk, bv, Qh, Kh, Vtw);
    attn_f16<<<1024, 128, 0, stream>>>(Qh, Kh, Vtw, out);
}

// Round 10
// 201.978 us; speedup vs baseline: 1.2515x; 1.2515x over previous
//
#include <hip/hip_runtime.h>
#include <math.h>

#define B_  2
#define S_  2048
#define D_  1024
#define H_  16
#define DH_ 64
#define M_  (B_ * S_)   // 4096

typedef _Float16 half_t;
typedef __attribute__((ext_vector_type(8))) _Float16 h8;
typedef __attribute__((ext_vector_type(4))) _Float16 h4;
typedef __attribute__((ext_vector_type(4))) float   f32x4;

#define LOG2E 1.44269504088896f

// async global->LDS, 16 B per lane (lane-contiguous dest, m104/m108)
__device__ __forceinline__ void gll16(const half_t* g, half_t* l) {
    __builtin_amdgcn_global_load_lds(
        (__attribute__((address_space(1))) const void*)g,
        (__attribute__((address_space(3))) void*)l, 16, 0, 0);
}

// ---------------------------------------------------------------------------
// Prepass (fused): blocks 0..2047 convert x fp32->fp16; blocks 2048..3583
// transpose W [k][n] fp32 -> Wt [n][k] fp16 (3 matrices).
// ---------------------------------------------------------------------------
__global__ __launch_bounds__(256) void prep_k(
    const float* __restrict__ x, half_t* __restrict__ xh,
    const float* __restrict__ Wq, const float* __restrict__ Wk,
    const float* __restrict__ Wv, half_t* __restrict__ Wt)
{
    const int bx = blockIdx.x;
    if (bx < 2048) {
        const size_t i = ((size_t)bx * 256 + threadIdx.x) * 8;
        const float4 a = *(const float4*)(x + i);
        const float4 b = *(const float4*)(x + i + 4);
        h8 o;
        o[0] = (half_t)a.x; o[1] = (half_t)a.y; o[2] = (half_t)a.z; o[3] = (half_t)a.w;
        o[4] = (half_t)b.x; o[5] = (half_t)b.y; o[6] = (half_t)b.z; o[7] = (half_t)b.w;
        *(h8*)(xh + i) = o;
    } else {
        const int gb    = bx - 2048;                 // 0..1535
        const int which = gb >> 9;
        const float* __restrict__ W = (which == 0) ? Wq : (which == 1) ? Wk : Wv;
        half_t* __restrict__ T = Wt + (size_t)which * D_ * D_;
        const int gw   = (gb & 511) * 4 + (threadIdx.x >> 6);   // 0..2047
        const int lane = threadIdx.x & 63;
        const int n    = (gw & 15) * 64 + lane;
        const int k0   = (gw >> 4) * 8;
        h8 o;
        #pragma unroll
        for (int t = 0; t < 8; ++t) o[t] = (half_t)W[(size_t)(k0 + t) * D_ + n];
        *(h8*)(T + (size_t)n * D_ + k0) = o;
    }
}

// ---------------------------------------------------------------------------
// Kernel 1: fused QKV projection (R6 known-good).  128x128 tile, BK=64,
// single-buffered global_load_lds into XOR-chunk-swizzled unpadded LDS.
// XCD-aware 1D-swizzled grid.  Epilogue: Q = tanh-GELU * log2e, K natural,
// V pre-transposed to Vt[bh][d][s].
// ---------------------------------------------------------------------------
__global__ __launch_bounds__(256) void qkv_gemm_f16(
    const half_t* __restrict__ xh, const half_t* __restrict__ Wt,
    const float* __restrict__ bq, const float* __restrict__ bk,
    const float* __restrict__ bv,
    half_t* __restrict__ Qo, half_t* __restrict__ Ko, half_t* __restrict__ Vt)
{
    const int bi = blockIdx.x;                       // 0..767
    const int mt = (bi & 7) * 4 + ((bi >> 3) & 3);   // 0..31
    const int nt = bi >> 5;                          // 0..23
    const int m0 = mt * 128;
    const int n0g = nt * 128;
    const int which = n0g >> 10;
    const int n0    = n0g & 1023;
    const half_t* __restrict__ Wp  = Wt + (size_t)which * D_ * D_;
    const float* __restrict__ bias = (which == 0) ? bq : (which == 1) ? bk : bv;

    const int tid = threadIdx.x, lane = tid & 63, wave = tid >> 6;
    const int wm = (wave >> 1) * 64, wn = (wave & 1) * 64;
    const int ln = lane & 15, quad = lane >> 4;

    __shared__ __align__(16) half_t As[128 * 64];   // swizzled slots
    __shared__ __align__(16) half_t Bs[128 * 64];

    f32x4 acc[4][4];
    #pragma unroll
    for (int i = 0; i < 4; ++i)
        #pragma unroll
        for (int j = 0; j < 4; ++j) acc[i][j] = (f32x4){0.f, 0.f, 0.f, 0.f};

    for (int k0 = 0; k0 < D_; k0 += 64) {
        __syncthreads();
        #pragma unroll
        for (int l = 0; l < 4; ++l) {
            const int c  = tid + l * 256;
            const int r  = c >> 3, c0 = c & 7;
            const int cs = c0 ^ (r & 7);
            gll16(xh + (size_t)(m0 + r) * D_ + k0 + cs * 8, &As[c * 8]);
            gll16(Wp + (size_t)(n0 + r) * D_ + k0 + cs * 8, &Bs[c * 8]);
        }
        __syncthreads();

        #pragma unroll
        for (int kc = 0; kc < 2; ++kc) {
            h8 af[4], bf[4];
            #pragma unroll
            for (int i = 0; i < 4; ++i) {
                const int r = wm + i * 16 + ln;
                af[i] = *(const h8*)&As[r * 64 + (((kc << 2) + quad) ^ (r & 7)) * 8];
            }
            #pragma unroll
            for (int j = 0; j < 4; ++j) {
                const int r = wn + j * 16 + ln;
                bf[j] = *(const h8*)&Bs[r * 64 + (((kc << 2) + quad) ^ (r & 7)) * 8];
            }
            #pragma unroll
            for (int i = 0; i < 4; ++i)
                #pragma unroll
                for (int j = 0; j < 4; ++j)
                    acc[i][j] = __builtin_amdgcn_mfma_f32_16x16x32_f16(
                        af[i], bf[j], acc[i][j], 0, 0, 0);
        }
    }

    if (which == 2) {
        #pragma unroll
        for (int j = 0; j < 4; ++j) {
            const int col = n0 + wn + j * 16 + ln;
            const int h = col >> 6, d = col & 63;
            const float bb = bias[col];
            #pragma unroll
            for (int i = 0; i < 4; ++i) {
                const int sg = m0 + wm + i * 16 + quad * 4;
                const int b  = sg >> 11, srow = sg & 2047;
                h4 pv;
                #pragma unroll
                for (int r = 0; r < 4; ++r) pv[r] = (half_t)(acc[i][j][r] + bb);
                *(h4*)(Vt + (((size_t)(b * H_ + h) * DH_ + d) * S_ + srow)) = pv;
            }
        }
    } else {
        half_t* __restrict__ out = (which == 0) ? Qo : Ko;
        #pragma unroll
        for (int j = 0; j < 4; ++j) {
            const int col = n0 + wn + j * 16 + ln;
            const float bb = bias[col];
            #pragma unroll
            for (int i = 0; i < 4; ++i) {
                #pragma unroll
                for (int r = 0; r < 4; ++r) {
                    const int row = m0 + wm + i * 16 + quad * 4 + r;
                    float t = acc[i][j][r] + bb;
                    if (which == 0) {
                        const float u = t * fmaf(t * t, 0.0356774081f, 0.7978845608f);
                        const float e = __builtin_amdgcn_exp2f(u * -2.88539008178f);
                        t = t * __builtin_amdgcn_rcpf(1.0f + e) * LOG2E;
                    }
                    out[(size_t)row * D_ + col] = (half_t)t;
                }
            }
        }
    }
}

// ---------------------------------------------------------------------------
// Kernel 2: flash attention, REGISTER-RESIDENT P.
// Key insight: S^T's C/D layout (lane holds keys 16j+4quad+r, r<4, of q-row
// ln) is EXACTLY the A-fragment layout of mfma_f32_16x16x16_f16
// (A[m=ln][k=quad*4+i]).  So P never touches LDS: pack exp2(s[j][0..3]) into
// an h4 and feed 16 K=16 PV MFMAs (+4 ones-MFMAs for l) per q-group.
// Removes 12 DS ops + the ds_write->lgkm->ds_read chain per wave-tile and
// the 9.2 KB Ps buffer (LDS = 16.4 KB).  V B-frags: b64 reads via the XOR
// swizzle (bank-count-optimal).  Single-buffer staging (R9 dbuf regressed).
// 2-wave blocks, 64 q-rows, 2 q-groups/wave, 1024 blocks.
// ---------------------------------------------------------------------------
__global__ __launch_bounds__(128) void attn_f16(
    const half_t* __restrict__ Q, const half_t* __restrict__ K,
    const half_t* __restrict__ Vt, float* __restrict__ out)
{
    const int tid  = threadIdx.x;
    const int lane = tid & 63;
    const int wave = tid >> 6;          // 0..1
    const int ln   = lane & 15;
    const int quad = lane >> 4;

    const int bi = blockIdx.x;                      // 0..1023
    const int bh = (bi & 7) * 4 + ((bi >> 3) & 3);  // 0..31 (XCD band)
    const int q0 = (bi >> 5) * 64;                  // 0..1984
    const int b  = bh >> 4;
    const int h  = bh & 15;

    const half_t* __restrict__ Qb  = Q  + (size_t)b * S_ * D_ + h * DH_;
    const half_t* __restrict__ Kb  = K  + (size_t)b * S_ * D_ + h * DH_;
    const half_t* __restrict__ Vtb = Vt + (size_t)bh * DH_ * S_;

    __shared__ __align__(16) half_t Ks[64 * 64];    // swizzled slots, 8 KB
    __shared__ __align__(16) half_t Vs[64 * 64];    // swizzled slots, 8 KB

    // ---- Q fragments, direct from global (one-time) ----
    const int qra = q0 + wave * 32 + ln;
    const h8 qa0 = *(const h8*)(Qb + (size_t)qra * D_ + quad * 8);
    const h8 qa1 = *(const h8*)(Qb + (size_t)qra * D_ + 32 + quad * 8);
    const h8 qc0 = *(const h8*)(Qb + (size_t)(qra + 16) * D_ + quad * 8);
    const h8 qc1 = *(const h8*)(Qb + (size_t)(qra + 16) * D_ + 32 + quad * 8);

    h4 ones4;
    #pragma unroll
    for (int t = 0; t < 4; ++t) ones4[t] = (half_t)1.0f;

    f32x4 Oa[4], Ob[4];
    #pragma unroll
    for (int j = 0; j < 4; ++j) {
        Oa[j] = (f32x4){0.f, 0.f, 0.f, 0.f};
        Ob[j] = (f32x4){0.f, 0.f, 0.f, 0.f};
    }
    f32x4 la = (f32x4){0.f, 0.f, 0.f, 0.f};
    f32x4 lb = (f32x4){0.f, 0.f, 0.f, 0.f};
    float m_a = -INFINITY, m_b = -INFINITY;

    for (int k0 = 0; k0 < S_; k0 += 64) {
        // ---- stage K and V via async DMA, swizzled ----
        __syncthreads();                   // previous tile fully consumed
        #pragma unroll
        for (int l = 0; l < 4; ++l) {
            const int c  = tid + l * 128;            // slot 0..511
            const int r  = c >> 3, c0 = c & 7;
            const int cs = c0 ^ (r & 7);
            gll16(Kb  + (size_t)(k0 + r) * D_ + cs * 8, &Ks[c * 8]);
            gll16(Vtb + (size_t)r * S_ + k0 + cs * 8,   &Vs[c * 8]);
        }
        __syncthreads();                   // DMA drained

        // ---- S^T = K Q^T for both q-groups (K=32 MFMAs) ----
        f32x4 sa[4], sb[4];
        #pragma unroll
        for (int j = 0; j < 4; ++j) {
            const int rK = j * 16 + ln;
            const h8 ka0 = *(const h8*)&Ks[rK * 64 + ((quad)     ^ (rK & 7)) * 8];
            const h8 ka1 = *(const h8*)&Ks[rK * 64 + ((quad + 4) ^ (rK & 7)) * 8];
            f32x4 tt = (f32x4){0.f, 0.f, 0.f, 0.f};
            tt = __builtin_amdgcn_mfma_f32_16x16x32_f16(ka0, qa0, tt, 0, 0, 0);
            tt = __builtin_amdgcn_mfma_f32_16x16x32_f16(ka1, qa1, tt, 0, 0, 0);
            sa[j] = tt;
            f32x4 u = (f32x4){0.f, 0.f, 0.f, 0.f};
            u = __builtin_amdgcn_mfma_f32_16x16x32_f16(ka0, qc0, u, 0, 0, 0);
            u = __builtin_amdgcn_mfma_f32_16x16x32_f16(ka1, qc1, u, 0, 0, 0);
            sb[j] = u;
        }

        // ---- online softmax (log2 domain), conditional rescale ----
        float mxa = sa[0][0], mxb = sb[0][0];
        #pragma unroll
        for (int j = 0; j < 4; ++j)
            #pragma unroll
            for (int r = 0; r < 4; ++r) {
                mxa = fmaxf(mxa, sa[j][r]);
                mxb = fmaxf(mxb, sb[j][r]);
            }
        mxa = fmaxf(mxa, __shfl_xor(mxa, 16, 64));
        mxa = fmaxf(mxa, __shfl_xor(mxa, 32, 64));
        mxb = fmaxf(mxb, __shfl_xor(mxb, 16, 64));
        mxb = fmaxf(mxb, __shfl_xor(mxb, 32, 64));

        if (__ballot(mxa > m_a || mxb > m_b)) {
            const float mna = fmaxf(m_a, mxa);
            const float mnb = fmaxf(m_b, mxb);
            const float ala = __builtin_amdgcn_exp2f(m_a - mna);
            const float alb = __builtin_amdgcn_exp2f(m_b - mnb);
            m_a = mna; m_b = mnb;
            float ra[4], rb[4];
            #pragma unroll
            for (int r = 0; r < 4; ++r) {
                ra[r] = __shfl(ala, quad * 4 + r, 64);
                rb[r] = __shfl(alb, quad * 4 + r, 64);
            }
            #pragma unroll
            for (int r = 0; r < 4; ++r) {
                la[r] *= ra[r]; lb[r] *= rb[r];
                #pragma unroll
                for (int j = 0; j < 4; ++j) { Oa[j][r] *= ra[r]; Ob[j][r] *= rb[r]; }
            }
        }

        // ---- P stays in registers: h4 A-fragments for K=16 MFMAs ----
        h4 pa4[4], pb4[4];
        #pragma unroll
        for (int j = 0; j < 4; ++j) {
            #pragma unroll
            for (int r = 0; r < 4; ++r) {
                pa4[j][r] = (half_t)__builtin_amdgcn_exp2f(sa[j][r] - m_a);
                pb4[j][r] = (half_t)__builtin_amdgcn_exp2f(sb[j][r] - m_b);
            }
        }

        // ---- l += P 1 (K=16 ones-MFMA, C-layout rows preserved) ----
        #pragma unroll
        for (int j = 0; j < 4; ++j) {
            la = __builtin_amdgcn_mfma_f32_16x16x16f16(pa4[j], ones4, la, 0, 0, 0);
            lb = __builtin_amdgcn_mfma_f32_16x16x16f16(pb4[j], ones4, lb, 0, 0, 0);
        }

        // ---- O += P V : 16 K=16 MFMAs per group, V B-frags b64-swizzled ----
        #pragma unroll
        for (int jd = 0; jd < 4; ++jd) {
            const int rV = jd * 16 + ln;
            h4 vbf[4];
            #pragma unroll
            for (int j = 0; j < 4; ++j) {
                const int slot = rV * 8 + ((2 * j + (quad >> 1)) ^ (rV & 7));
                vbf[j] = *(const h4*)&Vs[slot * 8 + 4 * (quad & 1)];
            }
            #pragma unroll
            for (int j = 0; j < 4; ++j) {
                Oa[jd] = __builtin_amdgcn_mfma_f32_16x16x16f16(pa4[j], vbf[j], Oa[jd], 0, 0, 0);
                Ob[jd] = __builtin_amdgcn_mfma_f32_16x16x16f16(pb4[j], vbf[j], Ob[jd], 0, 0, 0);
            }
        }
    }

    // ---- epilogue: normalize, store fp32 ----
    #pragma unroll
    for (int r = 0; r < 4; ++r) {
        const float iva = 1.0f / la[r];
        const float ivb = 1.0f / lb[r];
        const int rowa = q0 + wave * 32 + quad * 4 + r;
        const int rowb = rowa + 16;
        #pragma unroll
        for (int j = 0; j < 4; ++j) {
            out[((size_t)b * S_ + rowa) * D_ + h * DH_ + j * 16 + ln] = Oa[j][r] * iva;
            out[((size_t)b * S_ + rowb) * D_ + h * DH_ + j * 16 + ln] = Ob[j][r] * ivb;
        }
    }
}

// ---------------------------------------------------------------------------
extern "C" void kernel_launch(void* const* d_in, const int* in_sizes, int n_in,
                              void* d_out, int out_size, void* d_ws, size_t ws_size,
                              hipStream_t stream) {
    const float* x  = (const float*)d_in[0];
    const float* Wq = (const float*)d_in[1];
    const float* bq = (const float*)d_in[2];
    const float* Wk = (const float*)d_in[3];
    const float* bk = (const float*)d_in[4];
    const float* Wv = (const float*)d_in[5];
    const float* bv = (const float*)d_in[6];
    float* out = (float*)d_out;

    const size_t nmd = (size_t)M_ * D_;   // 4M
    const size_t ndd = (size_t)D_ * D_;   // 1M
    half_t* xh  = (half_t*)d_ws;          // 4M halves
    half_t* Wt  = xh + nmd;               // 3M
    half_t* Qh  = Wt + 3 * ndd;           // 4M
    half_t* Kh  = Qh + nmd;               // 4M
    half_t* Vtw = Kh + nmd;               // 4M  (38 MB total)

    prep_k<<<2048 + 1536, 256, 0, stream>>>(x, xh, Wq, Wk, Wv, Wt);
    qkv_gemm_f16<<<768, 256, 0, stream>>>(xh, Wt, bq, bk, bv, Qh, Kh, Vtw);
    attn_f16<<<1024, 128, 0, stream>>>(Qh, Kh, Vtw, out);
}